// Round 8
// baseline (351.118 us; speedup 1.0000x reference)
//
#include <hip/hip_runtime.h>
#include <hip/hip_bf16.h>

#define NSEQ 2048
#define DM 512
#define BATCH 8
#define GTOT (BATCH * NSEQ)          // 16384
#define INV_T 0.044194173824159216f  // 1/sqrt(512)
#define EPSN 1e-5f

typedef __bf16 bf16_t;
typedef bf16_t bf16x8 __attribute__((ext_vector_type(8)));
typedef float f32x16 __attribute__((ext_vector_type(16)));
typedef unsigned short u16;
typedef unsigned int u32;
typedef unsigned char u8;
typedef unsigned long long u64;

__device__ __forceinline__ u16 f2bf(float f) {
    u32 u = __builtin_bit_cast(u32, f);
    u32 r = (u + 0x7FFFu + ((u >> 16) & 1u)) >> 16;
    return (u16)r;
}

// async global->LDS DMA, 16 B per lane. LDS dest = wave-uniform base + lane*16 B.
__device__ __forceinline__ void async16(const u16* g, u16* l) {
    __builtin_amdgcn_global_load_lds(
        (const __attribute__((address_space(1))) u32*)g,
        (__attribute__((address_space(3))) u32*)l, 16, 0, 0);
}

#define MFMA32(a, b, c) __builtin_amdgcn_mfma_f32_32x32x16_bf16(a, b, c, 0, 0, 0)
#define ROWOFF(reg, lh) (((reg) & 3) + 8 * ((reg) >> 2) + 4 * (lh))

// BK=64 staging: 8 issues/thread (4 A + 4 B). Issue u = wave*4+j covers LDS rows
// u*8..u*8+7; lane supplies row u*8+(lane>>3), chunk (lane&7), fetching the
// global chunk that the swizzled frag read expects at that slot.
#define STAGE64(Ag, ldA, Bg, ldB, k0)                                            \
    do {                                                                         \
        _Pragma("unroll") for (int j = 0; j < 4; ++j) {                          \
            const int cg = (lane & 7) ^ ((j * 4 + (lane >> 4)) & 7);             \
            const int dst = (wave * 4 + j) * 512 + lane * 8;                     \
            async16((Ag) + (long)(rS + j * 8) * (ldA) + (k0) + cg * 8, Ab + dst);\
            async16((Bg) + (long)(rS + j * 8) * (ldB) + (k0) + cg * 8, Bb + dst);\
        }                                                                        \
    } while (0)

// Hoisted kt-invariant frag offsets. Rows r and r+32 share the same XOR swizzle
// ((r+32)>>1 & 7 == r>>1 & 7), so the +32-row frag is offset +2048 elems (imm-folded).
#define FRAG_OFFS(oA, oB)                                                        \
    int oA[4], oB[4];                                                            \
    do {                                                                         \
        const int ra = wy * 64 + l31, rb = wx * 64 + l31;                        \
        _Pragma("unroll") for (int ks = 0; ks < 4; ++ks) {                       \
            const int kc = ks * 2 + lh;                                          \
            oA[ks] = ra * 64 + ((kc ^ ((ra >> 1) & 7)) << 3);                    \
            oB[ks] = rb * 64 + ((kc ^ ((rb >> 1) & 7)) << 3);                    \
        }                                                                        \
    } while (0)

// ---- kernel 1: f32->bf16 of X and W; zero ssbuf; bit-pack mask (merged) ----
// Block ranges: [0,8192) X, [8192,8448) W, [8448,8464) ss, [8464,41232) mask.
__global__ __launch_bounds__(256) void k_convert(
    const float* __restrict__ X, const float* __restrict__ W,
    const float* __restrict__ mask,
    u16* __restrict__ Kbf, u16* __restrict__ Wbf,
    float* __restrict__ ssbuf, u64* __restrict__ Mbits) {
    __shared__ u8 nib[256];
    const int tid = threadIdx.x;
    const int bid = blockIdx.x;
    if (bid < 8192) {
        long i = (long)bid * 256 + tid;
        float4 f = ((const float4*)X)[i];
        ushort4 o;
        o.x = f2bf(f.x); o.y = f2bf(f.y); o.z = f2bf(f.z); o.w = f2bf(f.w);
        ((ushort4*)Kbf)[i] = o;
    } else if (bid < 8448) {
        long j = (long)(bid - 8192) * 256 + tid;
        float4 f = ((const float4*)W)[j];
        ushort4 o;
        o.x = f2bf(f.x); o.y = f2bf(f.y); o.z = f2bf(f.z); o.w = f2bf(f.w);
        ((ushort4*)Wbf)[j] = o;
    } else if (bid < 8464) {
        long j = (long)(bid - 8448) * 256 + tid;
        ((float4*)ssbuf)[j] = (float4){0.f, 0.f, 0.f, 0.f};
    } else {
        // mask bit-pack: 1024 floats/block -> 16 u64. 0.0f has bit pattern 0.
        const long mb = bid - 8464;
        uint4 f = ((const uint4*)mask)[mb * 256 + tid];
        unsigned n = (f.x ? 1u : 0u) | (f.y ? 2u : 0u) |
                     (f.z ? 4u : 0u) | (f.w ? 8u : 0u);
        nib[tid] = (u8)n;
        __syncthreads();
        if (tid < 16) {
            u64 w = 0;
#pragma unroll
            for (int i = 0; i < 16; ++i) w |= (u64)nib[tid * 16 + i] << (i * 4);
            Mbits[mb * 16 + tid] = w;
        }
    }
}

// --- kernel 2: S = bitmask .* (X X^T) * INV_T (bf16) + row sum-of-squares ---
// 128x128 tile, BK=64, 256 thr, 4 waves (2x2), wave tile 64x64.
__global__ __launch_bounds__(256, 4) void k_sgemm(
    const u16* __restrict__ Kbf, const u64* __restrict__ Mw,
    u16* __restrict__ Sbuf, float* __restrict__ ssbuf) {
    __shared__ __attribute__((aligned(16))) u16 Ab[8192], Bb[8192];
    const int tid = threadIdx.x, wave = tid >> 6, lane = tid & 63;
    const int l31 = lane & 31, lh = lane >> 5;
    const int wy = wave >> 1, wx = wave & 1;
    const int b = blockIdx.z;
    const int M0 = blockIdx.y * 128, N0 = blockIdx.x * 128;
    const u16* Ag = Kbf + (long)(b * NSEQ + M0) * DM;
    const u16* Bg = Kbf + (long)(b * NSEQ + N0) * DM;
    const u64* Mb = Mw + (long)b * NSEQ * 32;  // 32 u64 words per row

    const int rS = wave * 32 + (lane >> 3);
    FRAG_OFFS(oA, oB);

    f32x16 acc[2][2];
#pragma unroll
    for (int i = 0; i < 2; ++i)
#pragma unroll
        for (int j = 0; j < 2; ++j)
#pragma unroll
            for (int e = 0; e < 16; ++e) acc[i][j][e] = 0.f;

    for (int kt = 0; kt < 8; ++kt) {
        const int k0 = kt * 64;
        __syncthreads();
        STAGE64(Ag, DM, Bg, DM, k0);
        __syncthreads();
#pragma unroll
        for (int ks = 0; ks < 4; ++ks) {
            bf16x8 a0 = *(const bf16x8*)(Ab + oA[ks]);
            bf16x8 a1 = *(const bf16x8*)(Ab + oA[ks] + 2048);
            bf16x8 b0 = *(const bf16x8*)(Bb + oB[ks]);
            bf16x8 b1 = *(const bf16x8*)(Bb + oB[ks] + 2048);
            acc[0][0] = MFMA32(a0, b0, acc[0][0]);
            acc[0][1] = MFMA32(a0, b1, acc[0][1]);
            acc[1][0] = MFMA32(a1, b0, acc[1][0]);
            acc[1][1] = MFMA32(a1, b1, acc[1][1]);
        }
    }
    // epilogue: bitmask multiply, bf16 store, per-row sum-of-squares -> atomicAdd
#pragma unroll
    for (int mi = 0; mi < 2; ++mi) {
#pragma unroll
        for (int reg = 0; reg < 16; ++reg) {
            int rl = M0 + wy * 64 + mi * 32 + ROWOFF(reg, lh);
            long rg = (long)b * NSEQ + rl;
            // one aligned u64 covers this wave's 64-col window of the mask row
            u64 w = Mb[(long)rl * 32 + (N0 >> 6) + wx];
            float v = 0.f;
#pragma unroll
            for (int ni = 0; ni < 2; ++ni) {
                int cg = N0 + wx * 64 + ni * 32 + l31;
                float s = ((w >> (ni * 32 + l31)) & 1ull)
                              ? acc[mi][ni][reg] * INV_T : 0.f;
                v += s * s;
                Sbuf[rg * NSEQ + cg] = f2bf(s);
            }
            v += __shfl_xor(v, 1, 32);
            v += __shfl_xor(v, 2, 32);
            v += __shfl_xor(v, 4, 32);
            v += __shfl_xor(v, 8, 32);
            v += __shfl_xor(v, 16, 32);
            if (l31 == 0) atomicAdd(&ssbuf[rg], v);
        }
    }
}

// ------------- kernel 3: vT[e][g] = elu(W X^T + b), 128x128 BK=64 -------------
__global__ __launch_bounds__(256, 4) void k_vgemm(
    const u16* __restrict__ Wbf, const u16* __restrict__ Kbf,
    const float* __restrict__ bias, u16* __restrict__ vT) {
    __shared__ __attribute__((aligned(16))) u16 Ab[8192], Bb[8192];
    const int tid = threadIdx.x, wave = tid >> 6, lane = tid & 63;
    const int l31 = lane & 31, lh = lane >> 5;
    const int wy = wave >> 1, wx = wave & 1;
    const int M0 = blockIdx.y * 128, N0 = blockIdx.x * 128;
    const u16* Ag = Wbf + (long)M0 * DM;
    const u16* Bg = Kbf + (long)N0 * DM;

    const int rS = wave * 32 + (lane >> 3);
    FRAG_OFFS(oA, oB);

    f32x16 acc[2][2];
#pragma unroll
    for (int i = 0; i < 2; ++i)
#pragma unroll
        for (int j = 0; j < 2; ++j)
#pragma unroll
            for (int e = 0; e < 16; ++e) acc[i][j][e] = 0.f;

    for (int kt = 0; kt < 8; ++kt) {
        const int k0 = kt * 64;
        __syncthreads();
        STAGE64(Ag, DM, Bg, DM, k0);
        __syncthreads();
#pragma unroll
        for (int ks = 0; ks < 4; ++ks) {
            bf16x8 a0 = *(const bf16x8*)(Ab + oA[ks]);
            bf16x8 a1 = *(const bf16x8*)(Ab + oA[ks] + 2048);
            bf16x8 b0 = *(const bf16x8*)(Bb + oB[ks]);
            bf16x8 b1 = *(const bf16x8*)(Bb + oB[ks] + 2048);
            acc[0][0] = MFMA32(a0, b0, acc[0][0]);
            acc[0][1] = MFMA32(a0, b1, acc[0][1]);
            acc[1][0] = MFMA32(a1, b0, acc[1][0]);
            acc[1][1] = MFMA32(a1, b1, acc[1][1]);
        }
    }
#pragma unroll
    for (int mi = 0; mi < 2; ++mi) {
#pragma unroll
        for (int reg = 0; reg < 16; ++reg) {
            int e = M0 + wy * 64 + mi * 32 + ROWOFF(reg, lh);
            float bv = bias[e];
#pragma unroll
            for (int ni = 0; ni < 2; ++ni) {
                int g = N0 + wx * 64 + ni * 32 + l31;
                float x = acc[mi][ni][reg] + bv;
                float v = x > 0.f ? x : (__expf(x) - 1.f);
                vT[(long)e * GTOT + g] = f2bf(v);
            }
        }
    }
}

// -------- kernel 4: O = diag(1/max(||S_row||,eps)) * (S V), 128x128 BK=64 ------
// Per batch: M = 2048, N = 512 (d), K = 2048. A = S (bf16), B^T = vT.
__global__ __launch_bounds__(256, 4) void k_pv(
    const u16* __restrict__ Sbuf, const u16* __restrict__ vT,
    const float* __restrict__ ssbuf, float* __restrict__ Out) {
    __shared__ __attribute__((aligned(16))) u16 Ab[8192], Bb[8192];
    __shared__ float sc[128];
    const int tid = threadIdx.x, wave = tid >> 6, lane = tid & 63;
    const int l31 = lane & 31, lh = lane >> 5;
    const int wy = wave >> 1, wx = wave & 1;
    const int b = blockIdx.z;
    const int M0 = blockIdx.y * 128, N0 = blockIdx.x * 128;
    const u16* Ag = Sbuf + (long)(b * NSEQ + M0) * NSEQ;
    const u16* Bg = vT + (long)N0 * GTOT + b * NSEQ;

    if (tid < 128) {
        float v = ssbuf[b * NSEQ + M0 + tid];
        sc[tid] = 1.f / fmaxf(sqrtf(v), EPSN);
    }

    const int rS = wave * 32 + (lane >> 3);
    FRAG_OFFS(oA, oB);

    f32x16 acc[2][2];
#pragma unroll
    for (int i = 0; i < 2; ++i)
#pragma unroll
        for (int j = 0; j < 2; ++j)
#pragma unroll
            for (int e = 0; e < 16; ++e) acc[i][j][e] = 0.f;

    for (int kt = 0; kt < 32; ++kt) {
        const int k0 = kt * 64;
        __syncthreads();
        STAGE64(Ag, NSEQ, Bg, GTOT, k0);
        __syncthreads();
#pragma unroll
        for (int ks = 0; ks < 4; ++ks) {
            bf16x8 a0 = *(const bf16x8*)(Ab + oA[ks]);
            bf16x8 a1 = *(const bf16x8*)(Ab + oA[ks] + 2048);
            bf16x8 b0 = *(const bf16x8*)(Bb + oB[ks]);
            bf16x8 b1 = *(const bf16x8*)(Bb + oB[ks] + 2048);
            acc[0][0] = MFMA32(a0, b0, acc[0][0]);
            acc[0][1] = MFMA32(a0, b1, acc[0][1]);
            acc[1][0] = MFMA32(a1, b0, acc[1][0]);
            acc[1][1] = MFMA32(a1, b1, acc[1][1]);
        }
    }
#pragma unroll
    for (int mi = 0; mi < 2; ++mi) {
#pragma unroll
        for (int reg = 0; reg < 16; ++reg) {
            int rl = wy * 64 + mi * 32 + ROWOFF(reg, lh);
            float s = sc[rl];
            float* op = Out + ((long)b * NSEQ + M0 + rl) * DM;
#pragma unroll
            for (int ni = 0; ni < 2; ++ni) {
                int d = N0 + wx * 64 + ni * 32 + l31;
                op[d] = acc[mi][ni][reg] * s;
            }
        }
    }
}

extern "C" void kernel_launch(void* const* d_in, const int* in_sizes, int n_in,
                              void* d_out, int out_size, void* d_ws, size_t ws_size,
                              hipStream_t stream) {
    const float* X = (const float*)d_in[0];
    const float* mask = (const float*)d_in[1];
    const float* W = (const float*)d_in[2];
    const float* bias = (const float*)d_in[3];
    float* out = (float*)d_out;

    char* ws = (char*)d_ws;
    u16* Kbf = (u16*)ws;                           // 16 MiB
    u16* Wbf = (u16*)(ws + 16777216);              // 512 KiB
    u16* vT = (u16*)(ws + 17301504);               // 16 MiB
    u16* Sbuf = (u16*)(ws + 34078720);             // 64 MiB
    float* ssbuf = (float*)(ws + 101187584);       // 64 KiB
    u64* Mbits = (u64*)(ws + 101253120);           // 4 MiB (packed mask)

    k_convert<<<41232, 256, 0, stream>>>(X, W, mask, Kbf, Wbf, ssbuf, Mbits);
    k_vgemm<<<dim3(128, 4), 256, 0, stream>>>(Wbf, Kbf, bias, vT);
    k_sgemm<<<dim3(16, 16, 8), 256, 0, stream>>>(Kbf, Mbits, Sbuf, ssbuf);
    k_pv<<<dim3(4, 16, 8), 256, 0, stream>>>(Sbuf, vT, ssbuf, out);
}